// Round 1
// baseline (391.061 us; speedup 1.0000x reference)
//
#include <hip/hip_runtime.h>
#include <hip/hip_bf16.h>

// ---------------------------------------------------------------------------
// WaveletNauralNet: 9-level DWT -> 8 band reconstructions (h: 2048x32768,
// linear in x1) -> relu -> W0 (181x32768) -> relu -> W1 (13x181) -> relu ->
// W2 (10x13).  Strategy:
//   K1: W0 fp32 -> fp16, padded to 192 rows (rows 181..191 zero)
//   K2: per-row wavelet cascade entirely in LDS; writes relu(h) as fp16
//   K3: split-K MFMA fp16 GEMM (BM=128,BN=192,BK=64), partials fp32
//   K4: reduce partials + bias + tiny MLP layers 1..2
// ---------------------------------------------------------------------------

typedef _Float16 f16x8 __attribute__((ext_vector_type(8)));
typedef _Float16 f16x4v __attribute__((ext_vector_type(4)));
typedef float f32x4 __attribute__((ext_vector_type(4)));

#define WV_THREADS 256

// reconstruction filters (REC_LO / REC_HI from the reference)
__device__ __constant__ float c_lo[8] = {
    0.23037781330885523f,  0.7148465705525415f,  0.6308807679295904f,
   -0.02798376941698385f, -0.18703481171888114f, 0.030841381835986965f,
    0.032883011666982945f, -0.010597401784997278f};
__device__ __constant__ float c_hi[8] = {
   -0.010597401784997278f, -0.032883011666982945f, 0.030841381835986965f,
    0.18703481171888114f,  -0.02798376941698385f, -0.6308807679295904f,
    0.7148465705525415f,   -0.23037781330885523f};

// level lengths: NL[0]=input, NL[l]=len of a_l / d_l
// 4096 2051 1029 518 262 134 70 38 22 14 ; d-store offsets below
__device__ __forceinline__ int ext_idx(int j, int n) {
  // symmetric pad, left 6 / right 7 (after [:,1:])
  return (j < 6) ? (5 - j) : ((j < n + 6) ? (j - 6) : (2 * n + 5 - j));
}

// one DWT level: a (len n) -> anext (len m, lowpass), d (len m, highpass)
__device__ void dwt_level(const float* __restrict__ a, float* __restrict__ anext,
                          float* __restrict__ d, int n, int m, bool store_a) {
  const int tid = threadIdx.x;
  for (int i0 = tid * 8; i0 < m; i0 += WV_THREADS * 8) {
    float e[22];
#pragma unroll
    for (int q = 0; q < 22; ++q) {
      int j = 2 * i0 + q;
      int jm = n + 12;
      if (j > jm) j = jm;  // clamp (only unused slots)
      e[q] = a[ext_idx(j, n)];
    }
#pragma unroll
    for (int q = 0; q < 8; ++q) {
      int i = i0 + q;
      if (i < m) {
        float sl = 0.f, sh = 0.f;
#pragma unroll
        for (int k = 0; k < 8; ++k) {
          float v = e[2 * q + k];
          sl += v * c_lo[k];
          sh += v * c_hi[k];
        }
        if (store_a) anext[i] = sl;
        d[i] = sh;
      }
    }
  }
}

// one IDWT step. out[s] (s in [0,olen)) ; olen = 2n-6 where n = #coeffs used.
// pair u -> out[2u], out[2u+1] share window ca[u..u+3], cd[u..u+3].
template <bool HAS_CA, bool HAS_CD, bool FINAL>
__device__ void idwt_step(const float* __restrict__ ca, const float* __restrict__ cd,
                          float* __restrict__ outl, _Float16* __restrict__ outg,
                          int olen) {
  const int tid = threadIdx.x;
  const int npair = olen >> 1;
  const int imax = npair + 2;  // = n-1 (max coeff index used)
  for (int p0 = tid * 8; p0 < npair; p0 += WV_THREADS * 8) {
    float wa[11], wd[11];
    if (HAS_CA) {
#pragma unroll
      for (int q = 0; q < 11; ++q) {
        int ix = p0 + q; if (ix > imax) ix = imax;
        wa[q] = ca[ix];
      }
    }
    if (HAS_CD) {
#pragma unroll
      for (int q = 0; q < 11; ++q) {
        int ix = p0 + q; if (ix > imax) ix = imax;
        wd[q] = cd[ix];
      }
    }
#pragma unroll
    for (int q = 0; q < 8; ++q) {
      int u = p0 + q;
      if (u < npair) {
        float e = 0.f, o = 0.f;
        if (HAS_CA) {
          e = wa[q + 3] * c_lo[0] + wa[q + 2] * c_lo[2] + wa[q + 1] * c_lo[4] + wa[q] * c_lo[6];
          o = wa[q + 3] * c_lo[1] + wa[q + 2] * c_lo[3] + wa[q + 1] * c_lo[5] + wa[q] * c_lo[7];
        }
        if (HAS_CD) {
          e += wd[q + 3] * c_hi[0] + wd[q + 2] * c_hi[2] + wd[q + 1] * c_hi[4] + wd[q] * c_hi[6];
          o += wd[q + 3] * c_hi[1] + wd[q + 2] * c_hi[3] + wd[q + 1] * c_hi[5] + wd[q] * c_hi[7];
        }
        if (FINAL) {
          outg[2 * u]     = (_Float16)fmaxf(e, 0.f);
          outg[2 * u + 1] = (_Float16)fmaxf(o, 0.f);
        } else {
          outl[2 * u] = e;
          outl[2 * u + 1] = o;
        }
      }
    }
  }
}

__global__ __launch_bounds__(WV_THREADS) void wavelet_kernel(
    const float* __restrict__ x, _Float16* __restrict__ A) {
  __shared__ float bufX[4096];   // a0 / a2 / a4 ...
  __shared__ float bufA[2051];   // a1 / a3 ...
  __shared__ float dst[4138];    // d1..d9 packed
  __shared__ float sA[2052];
  __shared__ float sB[2052];
  const int NLa[10]   = {4096, 2051, 1029, 518, 262, 134, 70, 38, 22, 14};
  const int DOFFa[10] = {0, 0, 2051, 3080, 3598, 3860, 3994, 4064, 4102, 4124};
  const int row = blockIdx.x;
  const int tid = threadIdx.x;
  const float* xr = x + (size_t)row * 4096;
  for (int i = tid; i < 4096; i += WV_THREADS) bufX[i] = xr[i];
  __syncthreads();

  // analysis
  float* aprev = bufX;
  float* anext = bufA;
  for (int lev = 1; lev <= 9; ++lev) {
    dwt_level(aprev, anext, dst + DOFFa[lev], NLa[lev - 1], NLa[lev], lev < 9);
    __syncthreads();
    float* t = aprev; aprev = anext; anext = t;
  }

  // synthesis: rec_L from d_L (init cd) and d_{L-1} (first loop iter cd)
  _Float16* Ar = A + (size_t)row * 32768;
  for (int L = 2; L <= 9; ++L) {
    idwt_step<false, true, false>(nullptr, dst + DOFFa[L], sA, nullptr, 2 * NLa[L] - 6);
    __syncthreads();
    float* cur = sA;
    float* nxt = sB;
    for (int j = L - 2; j >= 1; --j) {
      int dlen = NLa[j + 1];
      if (j == L - 2)
        idwt_step<true, true, false>(cur, dst + DOFFa[j + 1], nxt, nullptr, 2 * dlen - 6);
      else
        idwt_step<true, false, false>(cur, nullptr, nxt, nullptr, 2 * dlen - 6);
      __syncthreads();
      float* t = cur; cur = nxt; nxt = t;
    }
    _Float16* og = Ar + (size_t)(L - 2) * 4096;
    if (L == 2)
      idwt_step<true, true, true>(cur, dst + DOFFa[1], nullptr, og, 4096);
    else
      idwt_step<true, false, true>(cur, nullptr, nullptr, og, 4096);
    __syncthreads();
  }
}

// ---------------------------------------------------------------------------
__global__ __launch_bounds__(256) void cvt_w0(const float* __restrict__ W0,
                                              _Float16* __restrict__ Bw) {
  size_t i = ((size_t)blockIdx.x * 256 + threadIdx.x) * 4;  // over 192*32768
  int rowc = (int)(i >> 15);
  f16x4v h;
  if (rowc < 181) {
    const float4 v = *(const float4*)(W0 + i);
    h[0] = (_Float16)v.x; h[1] = (_Float16)v.y;
    h[2] = (_Float16)v.z; h[3] = (_Float16)v.w;
  } else {
    h[0] = (_Float16)0.f; h[1] = (_Float16)0.f;
    h[2] = (_Float16)0.f; h[3] = (_Float16)0.f;
  }
  *(f16x4v*)(Bw + i) = h;
}

// ---------------------------------------------------------------------------
__device__ __forceinline__ void load_lds16(const void* g, void* l) {
  __builtin_amdgcn_global_load_lds((__attribute__((address_space(1))) unsigned int*)g,
                                   (__attribute__((address_space(3))) unsigned int*)l,
                                   16, 0, 0);
}

// C(2048x192) += A(2048x32768,f16) * Bw(192x32768,f16)^T, split-K partials.
// 16B-chunk XOR swizzle on global source; LDS linear => DMA writes conflict-free,
// frag ds_read_b128 2-way (free).
__global__ __launch_bounds__(256, 2) void gemm_kernel(
    const _Float16* __restrict__ A, const _Float16* __restrict__ Bw,
    float* __restrict__ P, int kchunk) {
  __shared__ _Float16 As[128 * 64];  // 16 KB
  __shared__ _Float16 Bs[192 * 64];  // 24 KB
  const int tid = threadIdx.x;
  const int lane = tid & 63;
  const int wave = tid >> 6;
  const int m0 = blockIdx.x * 128;
  const int k0 = blockIdx.y * kchunk;
  const int nstages = kchunk >> 6;

  f32x4 acc[2][12];
#pragma unroll
  for (int mt = 0; mt < 2; ++mt)
#pragma unroll
    for (int nt = 0; nt < 12; ++nt) acc[mt][nt] = (f32x4){0.f, 0.f, 0.f, 0.f};

  for (int ks = 0; ks < nstages; ++ks) {
    const int kbase = k0 + (ks << 6);
    __syncthreads();
#pragma unroll
    for (int t = 0; t < 4; ++t) {  // A tile: 16 wave-instrs total
      int g = ((wave * 4 + t) << 6) + lane;
      int r = g >> 3, cs = g & 7;
      const _Float16* gp = A + (size_t)(m0 + r) * 32768 + kbase + ((cs ^ (r & 7)) << 3);
      load_lds16(gp, (char*)As + (size_t)((wave * 4 + t) << 10));
    }
#pragma unroll
    for (int t = 0; t < 6; ++t) {  // B tile: 24 wave-instrs total
      int g = ((wave * 6 + t) << 6) + lane;
      int r = g >> 3, cs = g & 7;
      const _Float16* gp = Bw + (size_t)r * 32768 + kbase + ((cs ^ (r & 7)) << 3);
      load_lds16(gp, (char*)Bs + (size_t)((wave * 6 + t) << 10));
    }
    __syncthreads();
#pragma unroll
    for (int kk = 0; kk < 2; ++kk) {
      const int chunk = kk * 4 + (lane >> 4);
      f16x8 af[2];
#pragma unroll
      for (int mt = 0; mt < 2; ++mt) {
        int r = wave * 32 + mt * 16 + (lane & 15);
        af[mt] = *(const f16x8*)(As + r * 64 + ((chunk ^ (r & 7)) << 3));
      }
#pragma unroll
      for (int nt = 0; nt < 12; ++nt) {
        int rb = nt * 16 + (lane & 15);
        f16x8 bf = *(const f16x8*)(Bs + rb * 64 + ((chunk ^ (rb & 7)) << 3));
        acc[0][nt] = __builtin_amdgcn_mfma_f32_16x16x32_f16(af[0], bf, acc[0][nt], 0, 0, 0);
        acc[1][nt] = __builtin_amdgcn_mfma_f32_16x16x32_f16(af[1], bf, acc[1][nt], 0, 0, 0);
      }
    }
  }
  // epilogue: C/D layout col=lane&15, row=(lane>>4)*4+r
  float* Pp = P + ((size_t)blockIdx.y * 2048 + m0) * 192;
#pragma unroll
  for (int mt = 0; mt < 2; ++mt)
#pragma unroll
    for (int nt = 0; nt < 12; ++nt)
#pragma unroll
      for (int r4 = 0; r4 < 4; ++r4) {
        int rr = wave * 32 + mt * 16 + ((lane >> 4) << 2) + r4;
        int cc = nt * 16 + (lane & 15);
        Pp[(size_t)rr * 192 + cc] = acc[mt][nt][r4];
      }
}

// ---------------------------------------------------------------------------
__global__ __launch_bounds__(256) void mlp_kernel(
    const float* __restrict__ P, const float* __restrict__ b0,
    const float* __restrict__ W1, const float* __restrict__ b1,
    const float* __restrict__ W2, const float* __restrict__ b2,
    float* __restrict__ out, int nsplit) {
  __shared__ float h1[181];
  __shared__ float h2[13];
  const int row = blockIdx.x;
  const int t = threadIdx.x;
  if (t < 181) {
    float c = b0[t];
    for (int s = 0; s < nsplit; ++s)
      c += P[((size_t)s * 2048 + row) * 192 + t];
    h1[t] = fmaxf(c, 0.f);
  }
  __syncthreads();
  if (t < 13) {
    float c = b1[t];
    for (int n = 0; n < 181; ++n) c += h1[n] * W1[t * 181 + n];
    h2[t] = fmaxf(c, 0.f);
  }
  __syncthreads();
  if (t < 10) {
    float c = b2[t];
    for (int j = 0; j < 13; ++j) c += h2[j] * W2[t * 13 + j];
    out[(size_t)row * 10 + t] = c;
  }
}

// ---------------------------------------------------------------------------
extern "C" void kernel_launch(void* const* d_in, const int* in_sizes, int n_in,
                              void* d_out, int out_size, void* d_ws, size_t ws_size,
                              hipStream_t stream) {
  const float* x1 = (const float*)d_in[0];
  const float* W0 = (const float*)d_in[3];
  const float* b0 = (const float*)d_in[4];
  const float* W1 = (const float*)d_in[5];
  const float* b1 = (const float*)d_in[6];
  const float* W2 = (const float*)d_in[7];
  const float* b2 = (const float*)d_in[8];
  float* out = (float*)d_out;

  char* ws = (char*)d_ws;
  const size_t A_BYTES = (size_t)2048 * 32768 * 2;   // 134217728
  const size_t B_BYTES = (size_t)192 * 32768 * 2;    // 12582912
  _Float16* Afeat = (_Float16*)ws;
  _Float16* Bw = (_Float16*)(ws + A_BYTES);
  float* P = (float*)(ws + A_BYTES + B_BYTES);

  int nsplit = 32;
  while (nsplit > 1 &&
         A_BYTES + B_BYTES + (size_t)nsplit * 2048 * 192 * 4 > ws_size)
    nsplit >>= 1;

  cvt_w0<<<6144, 256, 0, stream>>>(W0, Bw);
  wavelet_kernel<<<2048, WV_THREADS, 0, stream>>>(x1, Afeat);
  dim3 gg(16, nsplit);
  gemm_kernel<<<gg, 256, 0, stream>>>(Afeat, Bw, P, 32768 / nsplit);
  mlp_kernel<<<2048, 256, 0, stream>>>(P, b0, W1, b1, W2, b2, out, nsplit);
}

// Round 2
// 274.610 us; speedup vs baseline: 1.4241x; 1.4241x over previous
//
#include <hip/hip_runtime.h>
#include <hip/hip_bf16.h>

// ---------------------------------------------------------------------------
// WaveletNauralNet: 9-level DWT -> 8 band reconstructions (h: 2048x32768,
// linear in x1) -> relu -> W0 (181x32768) -> relu -> W1 (13x181) -> relu ->
// W2 (10x13).
//   K1: W0 fp32 -> fp16, padded to 192 rows
//   K2: per-row wavelet cascade in LDS (stride-1 lanes, f2/f4 LDS ops,
//       41.2 KB LDS -> 3 blocks/CU), writes relu(h) fp16
//   K3: split-K MFMA fp16 GEMM (BM=128,BN=192,BK=64), fp32 partials
//   K4: reduce partials + bias + tiny MLP layers 1..2
// ---------------------------------------------------------------------------

typedef _Float16 f16x8 __attribute__((ext_vector_type(8)));
typedef _Float16 f16x4v __attribute__((ext_vector_type(4)));
typedef float f32x4 __attribute__((ext_vector_type(4)));

#define WV_THREADS 256

// reconstruction filters
#define L0 0.23037781330885523f
#define L1 0.7148465705525415f
#define L2f 0.6308807679295904f
#define L3 -0.02798376941698385f
#define L4 -0.18703481171888114f
#define L5 0.030841381835986965f
#define L6 0.032883011666982945f
#define L7 -0.010597401784997278f

#define H0 -0.010597401784997278f
#define H1 -0.032883011666982945f
#define H2 0.030841381835986965f
#define H3 0.18703481171888114f
#define H4 -0.02798376941698385f
#define H5 -0.6308807679295904f
#define H6 0.7148465705525415f
#define H7 -0.23037781330885523f

// symmetric pad, left 6 / right 7 (after [:,1:])
__device__ __forceinline__ int ext_idx(int j, int n) {
  return (j < 6) ? (5 - j) : ((j < n + 6) ? (j - 6) : (2 * n + 5 - j));
}

// one DWT level, 2 outputs per thread (i = 2g, 2g+1), stride-1 g across lanes.
// interior fast path: 5x ds_read_b64 (lane stride 16B).
__device__ __forceinline__ void dwt2(const float* a, float* anext, float* d,
                                     int n, int m, bool store_a) {
  const int ng = (m + 1) >> 1;
  for (int g = threadIdx.x; g < ng; g += WV_THREADS) {
    float w[10];
    if (g >= 2 && 4 * g + 9 <= n + 5) {
      const float2* af = (const float2*)a + (2 * g - 3);
      float2 b0 = af[0], b1 = af[1], b2 = af[2], b3 = af[3], b4 = af[4];
      w[0] = b0.x; w[1] = b0.y; w[2] = b1.x; w[3] = b1.y; w[4] = b2.x;
      w[5] = b2.y; w[6] = b3.x; w[7] = b3.y; w[8] = b4.x; w[9] = b4.y;
    } else {
#pragma unroll
      for (int q = 0; q < 10; ++q) {
        int j = 4 * g + q;
        int jm = n + 12;
        if (j > jm) j = jm;
        w[q] = a[ext_idx(j, n)];
      }
    }
    float sl0 = w[0]*L0 + w[1]*L1 + w[2]*L2f + w[3]*L3 + w[4]*L4 + w[5]*L5 + w[6]*L6 + w[7]*L7;
    float sh0 = w[0]*H0 + w[1]*H1 + w[2]*H2  + w[3]*H3 + w[4]*H4 + w[5]*H5 + w[6]*H6 + w[7]*H7;
    float sl1 = w[2]*L0 + w[3]*L1 + w[4]*L2f + w[5]*L3 + w[6]*L4 + w[7]*L5 + w[8]*L6 + w[9]*L7;
    float sh1 = w[2]*H0 + w[3]*H1 + w[4]*H2  + w[5]*H3 + w[6]*H4 + w[7]*H5 + w[8]*H6 + w[9]*H7;
    if (2 * g + 1 < m) {
      if (store_a) *(float2*)(anext + 2 * g) = make_float2(sl0, sl1);
      *(float2*)(d + 2 * g) = make_float2(sh0, sh1);
    } else {
      if (store_a) anext[2 * g] = sl0;
      d[2 * g] = sh0;
    }
  }
}

// one IDWT step, 2 pairs (4 outputs) per thread; ds_read_b64 lane stride 8B
// (conflict-free). dlen drives indexing: npair = dlen-3, olen = 2*dlen-6,
// reads coeffs[0..dlen-1] (implicit trim of +1-length ca).
template <bool HAS_CA, bool HAS_CD, bool FINAL>
__device__ __forceinline__ void idwt2(const float* ca, const float* cd,
                                      float* outl, _Float16* outg, int dlen) {
  const int npair = dlen - 3;
  const int ng = (npair + 1) >> 1;
  for (int g = threadIdx.x; g < ng; g += WV_THREADS) {
    float e0 = 0.f, o0 = 0.f, e1 = 0.f, o1 = 0.f;
    if (HAS_CA) {
      const float2* f = (const float2*)ca + g;
      float2 a0 = f[0], a1 = f[1], a2 = f[2];
      e0 = a1.y*L0 + a1.x*L2f + a0.y*L4 + a0.x*L6;
      o0 = a1.y*L1 + a1.x*L3  + a0.y*L5 + a0.x*L7;
      e1 = a2.x*L0 + a1.y*L2f + a1.x*L4 + a0.y*L6;
      o1 = a2.x*L1 + a1.y*L3  + a1.x*L5 + a0.y*L7;
    }
    if (HAS_CD) {
      const float2* f = (const float2*)cd + g;
      float2 d0 = f[0], d1 = f[1], d2 = f[2];
      e0 += d1.y*H0 + d1.x*H2 + d0.y*H4 + d0.x*H6;
      o0 += d1.y*H1 + d1.x*H3 + d0.y*H5 + d0.x*H7;
      e1 += d2.x*H0 + d1.y*H2 + d1.x*H4 + d0.y*H6;
      o1 += d2.x*H1 + d1.y*H3 + d1.x*H5 + d0.y*H7;
    }
    bool full = (2 * g + 1 < npair);
    if (FINAL) {
      if (full) {
        f16x4v h;
        h[0] = (_Float16)fmaxf(e0, 0.f); h[1] = (_Float16)fmaxf(o0, 0.f);
        h[2] = (_Float16)fmaxf(e1, 0.f); h[3] = (_Float16)fmaxf(o1, 0.f);
        *(f16x4v*)(outg + 4 * g) = h;
      } else {
        outg[4 * g]     = (_Float16)fmaxf(e0, 0.f);
        outg[4 * g + 1] = (_Float16)fmaxf(o0, 0.f);
      }
    } else {
      if (full) *(float4*)(outl + 4 * g) = make_float4(e0, o0, e1, o1);
      else      *(float2*)(outl + 4 * g) = make_float2(e0, o0);
    }
  }
}

// LDS layout (floats): r1[4104] | r2[2056] | dd[4144]  = 41216 B -> 3 blk/CU
// dd holds d1..d9 at even offsets (8B alignment for float2 reads).
__global__ __launch_bounds__(WV_THREADS) void wavelet_kernel(
    const float* __restrict__ x, _Float16* __restrict__ A) {
  __shared__ float lds[10304];
  float* r1 = lds;
  float* r2 = lds + 4104;
  float* dd = lds + 6160;
  const int NLa[10]  = {4096, 2051, 1029, 518, 262, 134, 70, 38, 22, 14};
  const int DOFF[10] = {0, 0, 2052, 3082, 3600, 3862, 3996, 4066, 4104, 4126};
  const int row = blockIdx.x;
  const int tid = threadIdx.x;

  const float4* xr = (const float4*)(x + (size_t)row * 4096);
  for (int i = tid; i < 1024; i += WV_THREADS) ((float4*)r1)[i] = xr[i];
  __syncthreads();

  // analysis: a-levels ping-pong r1<->r2, d-levels into dd
  {
    const float* ap = r1;
    float* an = r2;
    for (int lev = 1; lev <= 9; ++lev) {
      dwt2(ap, an, dd + DOFF[lev], NLa[lev - 1], NLa[lev], lev < 9);
      __syncthreads();
      const float* t = ap; ap = an; an = (float*)t;
    }
  }

  // synthesis: rec_L from d_L, then d_{L-1}, then zeros; r1/r2 as scratch
  _Float16* Ar = A + (size_t)row * 32768;
  for (int L = 2; L <= 9; ++L) {
    idwt2<false, true, false>(nullptr, dd + DOFF[L], r1, nullptr, NLa[L]);
    __syncthreads();
    float* cur = r1;
    float* nxt = r2;
    for (int j = L - 2; j >= 1; --j) {
      if (j == L - 2)
        idwt2<true, true, false>(cur, dd + DOFF[j + 1], nxt, nullptr, NLa[j + 1]);
      else
        idwt2<true, false, false>(cur, nullptr, nxt, nullptr, NLa[j + 1]);
      __syncthreads();
      float* t = cur; cur = nxt; nxt = t;
    }
    _Float16* og = Ar + (size_t)(L - 2) * 4096;
    if (L == 2)
      idwt2<true, true, true>(cur, dd + DOFF[1], nullptr, og, 2051);
    else
      idwt2<true, false, true>(cur, nullptr, nullptr, og, 2051);
    __syncthreads();
  }
}

// ---------------------------------------------------------------------------
__global__ __launch_bounds__(256) void cvt_w0(const float* __restrict__ W0,
                                              _Float16* __restrict__ Bw) {
  size_t i = ((size_t)blockIdx.x * 256 + threadIdx.x) * 4;  // over 192*32768
  int rowc = (int)(i >> 15);
  f16x4v h;
  if (rowc < 181) {
    const float4 v = *(const float4*)(W0 + i);
    h[0] = (_Float16)v.x; h[1] = (_Float16)v.y;
    h[2] = (_Float16)v.z; h[3] = (_Float16)v.w;
  } else {
    h[0] = (_Float16)0.f; h[1] = (_Float16)0.f;
    h[2] = (_Float16)0.f; h[3] = (_Float16)0.f;
  }
  *(f16x4v*)(Bw + i) = h;
}

// ---------------------------------------------------------------------------
__device__ __forceinline__ void load_lds16(const void* g, void* l) {
  __builtin_amdgcn_global_load_lds((__attribute__((address_space(1))) unsigned int*)g,
                                   (__attribute__((address_space(3))) unsigned int*)l,
                                   16, 0, 0);
}

// C(2048x192) += A(2048x32768,f16) * Bw(192x32768,f16)^T, split-K partials.
__global__ __launch_bounds__(256, 2) void gemm_kernel(
    const _Float16* __restrict__ A, const _Float16* __restrict__ Bw,
    float* __restrict__ P, int kchunk) {
  __shared__ _Float16 As[128 * 64];  // 16 KB
  __shared__ _Float16 Bs[192 * 64];  // 24 KB
  const int tid = threadIdx.x;
  const int lane = tid & 63;
  const int wave = tid >> 6;
  const int m0 = blockIdx.x * 128;
  const int k0 = blockIdx.y * kchunk;
  const int nstages = kchunk >> 6;

  f32x4 acc[2][12];
#pragma unroll
  for (int mt = 0; mt < 2; ++mt)
#pragma unroll
    for (int nt = 0; nt < 12; ++nt) acc[mt][nt] = (f32x4){0.f, 0.f, 0.f, 0.f};

  for (int ks = 0; ks < nstages; ++ks) {
    const int kbase = k0 + (ks << 6);
    __syncthreads();
#pragma unroll
    for (int t = 0; t < 4; ++t) {
      int g = ((wave * 4 + t) << 6) + lane;
      int r = g >> 3, cs = g & 7;
      const _Float16* gp = A + (size_t)(m0 + r) * 32768 + kbase + ((cs ^ (r & 7)) << 3);
      load_lds16(gp, (char*)As + (size_t)((wave * 4 + t) << 10));
    }
#pragma unroll
    for (int t = 0; t < 6; ++t) {
      int g = ((wave * 6 + t) << 6) + lane;
      int r = g >> 3, cs = g & 7;
      const _Float16* gp = Bw + (size_t)r * 32768 + kbase + ((cs ^ (r & 7)) << 3);
      load_lds16(gp, (char*)Bs + (size_t)((wave * 6 + t) << 10));
    }
    __syncthreads();
#pragma unroll
    for (int kk = 0; kk < 2; ++kk) {
      const int chunk = kk * 4 + (lane >> 4);
      f16x8 af[2];
#pragma unroll
      for (int mt = 0; mt < 2; ++mt) {
        int r = wave * 32 + mt * 16 + (lane & 15);
        af[mt] = *(const f16x8*)(As + r * 64 + ((chunk ^ (r & 7)) << 3));
      }
#pragma unroll
      for (int nt = 0; nt < 12; ++nt) {
        int rb = nt * 16 + (lane & 15);
        f16x8 bf = *(const f16x8*)(Bs + rb * 64 + ((chunk ^ (rb & 7)) << 3));
        acc[0][nt] = __builtin_amdgcn_mfma_f32_16x16x32_f16(af[0], bf, acc[0][nt], 0, 0, 0);
        acc[1][nt] = __builtin_amdgcn_mfma_f32_16x16x32_f16(af[1], bf, acc[1][nt], 0, 0, 0);
      }
    }
  }
  float* Pp = P + ((size_t)blockIdx.y * 2048 + m0) * 192;
#pragma unroll
  for (int mt = 0; mt < 2; ++mt)
#pragma unroll
    for (int nt = 0; nt < 12; ++nt)
#pragma unroll
      for (int r4 = 0; r4 < 4; ++r4) {
        int rr = wave * 32 + mt * 16 + ((lane >> 4) << 2) + r4;
        int cc = nt * 16 + (lane & 15);
        Pp[(size_t)rr * 192 + cc] = acc[mt][nt][r4];
      }
}

// ---------------------------------------------------------------------------
__global__ __launch_bounds__(256) void mlp_kernel(
    const float* __restrict__ P, const float* __restrict__ b0,
    const float* __restrict__ W1, const float* __restrict__ b1,
    const float* __restrict__ W2, const float* __restrict__ b2,
    float* __restrict__ out, int nsplit) {
  __shared__ float h1[181];
  __shared__ float h2[13];
  const int row = blockIdx.x;
  const int t = threadIdx.x;
  if (t < 181) {
    float c = b0[t];
    for (int s = 0; s < nsplit; ++s)
      c += P[((size_t)s * 2048 + row) * 192 + t];
    h1[t] = fmaxf(c, 0.f);
  }
  __syncthreads();
  if (t < 13) {
    float c = b1[t];
    for (int n = 0; n < 181; ++n) c += h1[n] * W1[t * 181 + n];
    h2[t] = fmaxf(c, 0.f);
  }
  __syncthreads();
  if (t < 10) {
    float c = b2[t];
    for (int j = 0; j < 13; ++j) c += h2[j] * W2[t * 13 + j];
    out[(size_t)row * 10 + t] = c;
  }
}

// ---------------------------------------------------------------------------
extern "C" void kernel_launch(void* const* d_in, const int* in_sizes, int n_in,
                              void* d_out, int out_size, void* d_ws, size_t ws_size,
                              hipStream_t stream) {
  const float* x1 = (const float*)d_in[0];
  const float* W0 = (const float*)d_in[3];
  const float* b0 = (const float*)d_in[4];
  const float* W1 = (const float*)d_in[5];
  const float* b1 = (const float*)d_in[6];
  const float* W2 = (const float*)d_in[7];
  const float* b2 = (const float*)d_in[8];
  float* out = (float*)d_out;

  char* ws = (char*)d_ws;
  const size_t A_BYTES = (size_t)2048 * 32768 * 2;
  const size_t B_BYTES = (size_t)192 * 32768 * 2;
  _Float16* Afeat = (_Float16*)ws;
  _Float16* Bw = (_Float16*)(ws + A_BYTES);
  float* P = (float*)(ws + A_BYTES + B_BYTES);

  int nsplit = 32;
  while (nsplit > 1 &&
         A_BYTES + B_BYTES + (size_t)nsplit * 2048 * 192 * 4 > ws_size)
    nsplit >>= 1;

  cvt_w0<<<6144, 256, 0, stream>>>(W0, Bw);
  wavelet_kernel<<<2048, WV_THREADS, 0, stream>>>(x1, Afeat);
  dim3 gg(16, nsplit);
  gemm_kernel<<<gg, 256, 0, stream>>>(Afeat, Bw, P, 32768 / nsplit);
  mlp_kernel<<<2048, 256, 0, stream>>>(P, b0, W1, b1, W2, b2, out, nsplit);
}

// Round 3
// 242.839 us; speedup vs baseline: 1.6104x; 1.1308x over previous
//
#include <hip/hip_runtime.h>
#include <hip/hip_bf16.h>

// ---------------------------------------------------------------------------
// WaveletNauralNet: 9-level DWT -> 8 band reconstructions (h: 2048x32768,
// linear in x1) -> relu -> W0 (181x32768) -> relu -> W1 (13x181) -> relu ->
// W2 (10x13).
//   K1: W0 fp32 -> fp16, padded to 192 rows
//   K2a: per-row analysis (9 DWT levels), d1..d9 -> global (aliases P region)
//   K2b: per-(row,L) synthesis block: rec_L cascade, writes relu(h) fp16
//   K3: split-K MFMA fp16 GEMM (BM=128,BN=192,BK=64), fp32 partials
//   K4: reduce partials + bias + tiny MLP layers 1..2
// ---------------------------------------------------------------------------

typedef _Float16 f16x8 __attribute__((ext_vector_type(8)));
typedef _Float16 f16x4v __attribute__((ext_vector_type(4)));
typedef float f32x4 __attribute__((ext_vector_type(4)));

#define WV_THREADS 256
#define DROW 4144  // per-row float stride of packed d1..d9 (4140 used + pad)

// reconstruction filters
#define L0 0.23037781330885523f
#define L1 0.7148465705525415f
#define L2f 0.6308807679295904f
#define L3 -0.02798376941698385f
#define L4 -0.18703481171888114f
#define L5 0.030841381835986965f
#define L6 0.032883011666982945f
#define L7 -0.010597401784997278f

#define H0 -0.010597401784997278f
#define H1 -0.032883011666982945f
#define H2 0.030841381835986965f
#define H3 0.18703481171888114f
#define H4 -0.02798376941698385f
#define H5 -0.6308807679295904f
#define H6 0.7148465705525415f
#define H7 -0.23037781330885523f

// symmetric pad, left 6 / right 7 (after [:,1:])
__device__ __forceinline__ int ext_idx(int j, int n) {
  return (j < 6) ? (5 - j) : ((j < n + 6) ? (j - 6) : (2 * n + 5 - j));
}

// one DWT level, 2 outputs per thread (i = 2g, 2g+1), stride-1 g across lanes.
// a/anext in LDS; d may be a global pointer (coalesced float2 stores).
__device__ __forceinline__ void dwt2(const float* a, float* anext, float* d,
                                     int n, int m, bool store_a) {
  const int ng = (m + 1) >> 1;
  for (int g = threadIdx.x; g < ng; g += WV_THREADS) {
    float w[10];
    if (g >= 2 && 4 * g + 9 <= n + 5) {
      const float2* af = (const float2*)a + (2 * g - 3);
      float2 b0 = af[0], b1 = af[1], b2 = af[2], b3 = af[3], b4 = af[4];
      w[0] = b0.x; w[1] = b0.y; w[2] = b1.x; w[3] = b1.y; w[4] = b2.x;
      w[5] = b2.y; w[6] = b3.x; w[7] = b3.y; w[8] = b4.x; w[9] = b4.y;
    } else {
#pragma unroll
      for (int q = 0; q < 10; ++q) {
        int j = 4 * g + q;
        int jm = n + 12;
        if (j > jm) j = jm;
        w[q] = a[ext_idx(j, n)];
      }
    }
    float sl0 = w[0]*L0 + w[1]*L1 + w[2]*L2f + w[3]*L3 + w[4]*L4 + w[5]*L5 + w[6]*L6 + w[7]*L7;
    float sh0 = w[0]*H0 + w[1]*H1 + w[2]*H2  + w[3]*H3 + w[4]*H4 + w[5]*H5 + w[6]*H6 + w[7]*H7;
    float sl1 = w[2]*L0 + w[3]*L1 + w[4]*L2f + w[5]*L3 + w[6]*L4 + w[7]*L5 + w[8]*L6 + w[9]*L7;
    float sh1 = w[2]*H0 + w[3]*H1 + w[4]*H2  + w[5]*H3 + w[6]*H4 + w[7]*H5 + w[8]*H6 + w[9]*H7;
    if (2 * g + 1 < m) {
      if (store_a) *(float2*)(anext + 2 * g) = make_float2(sl0, sl1);
      *(float2*)(d + 2 * g) = make_float2(sh0, sh1);
    } else {
      if (store_a) anext[2 * g] = sl0;
      d[2 * g] = sh0;
    }
  }
}

// one IDWT step, 2 pairs (4 outputs) per thread. dlen drives indexing:
// npair = dlen-3, olen = 2*dlen-6, reads coeffs[0..dlen-1] (implicit trim).
// ca in LDS; cd may be global (first 1-2 steps of each cascade).
template <bool HAS_CA, bool HAS_CD, bool FINAL>
__device__ __forceinline__ void idwt2(const float* ca, const float* cd,
                                      float* outl, _Float16* outg, int dlen) {
  const int npair = dlen - 3;
  const int ng = (npair + 1) >> 1;
  for (int g = threadIdx.x; g < ng; g += WV_THREADS) {
    float e0 = 0.f, o0 = 0.f, e1 = 0.f, o1 = 0.f;
    if (HAS_CA) {
      const float2* f = (const float2*)ca + g;
      float2 a0 = f[0], a1 = f[1], a2 = f[2];
      e0 = a1.y*L0 + a1.x*L2f + a0.y*L4 + a0.x*L6;
      o0 = a1.y*L1 + a1.x*L3  + a0.y*L5 + a0.x*L7;
      e1 = a2.x*L0 + a1.y*L2f + a1.x*L4 + a0.y*L6;
      o1 = a2.x*L1 + a1.y*L3  + a1.x*L5 + a0.y*L7;
    }
    if (HAS_CD) {
      const float2* f = (const float2*)cd + g;
      float2 d0 = f[0], d1 = f[1], d2 = f[2];
      e0 += d1.y*H0 + d1.x*H2 + d0.y*H4 + d0.x*H6;
      o0 += d1.y*H1 + d1.x*H3 + d0.y*H5 + d0.x*H7;
      e1 += d2.x*H0 + d1.y*H2 + d1.x*H4 + d0.y*H6;
      o1 += d2.x*H1 + d1.y*H3 + d1.x*H5 + d0.y*H7;
    }
    bool full = (2 * g + 1 < npair);
    if (FINAL) {
      if (full) {
        f16x4v h;
        h[0] = (_Float16)fmaxf(e0, 0.f); h[1] = (_Float16)fmaxf(o0, 0.f);
        h[2] = (_Float16)fmaxf(e1, 0.f); h[3] = (_Float16)fmaxf(o1, 0.f);
        *(f16x4v*)(outg + 4 * g) = h;
      } else {
        outg[4 * g]     = (_Float16)fmaxf(e0, 0.f);
        outg[4 * g + 1] = (_Float16)fmaxf(o0, 0.f);
      }
    } else {
      if (full) *(float4*)(outl + 4 * g) = make_float4(e0, o0, e1, o1);
      else      *(float2*)(outl + 4 * g) = make_float2(e0, o0);
    }
  }
}

// ---------------------------------------------------------------------------
// Analysis: one block per row, 9 DWT levels, d1..d9 -> global (DROW stride).
// LDS 24.6 KB -> 6 blocks/CU. 9 barriers.
__global__ __launch_bounds__(WV_THREADS) void wv_analysis(
    const float* __restrict__ x, float* __restrict__ dG) {
  __shared__ float r1[4104];
  __shared__ float r2[2056];
  const int NLa[10]  = {4096, 2051, 1029, 518, 262, 134, 70, 38, 22, 14};
  const int DOFF[10] = {0, 0, 2052, 3082, 3600, 3862, 3996, 4066, 4104, 4126};
  const int row = blockIdx.x;
  const int tid = threadIdx.x;

  const float4* xr = (const float4*)(x + (size_t)row * 4096);
  for (int i = tid; i < 1024; i += WV_THREADS) ((float4*)r1)[i] = xr[i];
  __syncthreads();

  float* dr = dG + (size_t)row * DROW;
  const float* ap = r1;
  float* an = r2;
  for (int lev = 1; lev <= 9; ++lev) {
    dwt2(ap, an, dr + DOFF[lev], NLa[lev - 1], NLa[lev], lev < 9);
    __syncthreads();
    const float* t = ap; ap = an; an = (float*)t;
  }
}

// ---------------------------------------------------------------------------
// Synthesis: one block per (row, L=2+blockIdx.y): rec_L cascade.
// LDS 16.4 KB -> 8 blocks/CU (32 waves). <=8 barriers per block.
__global__ __launch_bounds__(WV_THREADS, 6) void wv_synth(
    const float* __restrict__ dG, _Float16* __restrict__ A) {
  __shared__ float s1[2052];
  __shared__ float s2[2052];
  const int NLa[10]  = {4096, 2051, 1029, 518, 262, 134, 70, 38, 22, 14};
  const int DOFF[10] = {0, 0, 2052, 3082, 3600, 3862, 3996, 4066, 4104, 4126};
  const int row = blockIdx.x;
  const int L = 2 + blockIdx.y;
  const float* dr = dG + (size_t)row * DROW;

  idwt2<false, true, false>(nullptr, dr + DOFF[L], s1, nullptr, NLa[L]);
  __syncthreads();
  float* cur = s1;
  float* nxt = s2;
  for (int j = L - 2; j >= 1; --j) {
    if (j == L - 2)
      idwt2<true, true, false>(cur, dr + DOFF[j + 1], nxt, nullptr, NLa[j + 1]);
    else
      idwt2<true, false, false>(cur, nullptr, nxt, nullptr, NLa[j + 1]);
    __syncthreads();
    float* t = cur; cur = nxt; nxt = t;
  }
  _Float16* og = A + (size_t)row * 32768 + (size_t)(L - 2) * 4096;
  if (L == 2)
    idwt2<true, true, true>(cur, dr + DOFF[1], nullptr, og, 2051);
  else
    idwt2<true, false, true>(cur, nullptr, nullptr, og, 2051);
}

// ---------------------------------------------------------------------------
__global__ __launch_bounds__(256) void cvt_w0(const float* __restrict__ W0,
                                              _Float16* __restrict__ Bw) {
  size_t i = ((size_t)blockIdx.x * 256 + threadIdx.x) * 4;  // over 192*32768
  int rowc = (int)(i >> 15);
  f16x4v h;
  if (rowc < 181) {
    const float4 v = *(const float4*)(W0 + i);
    h[0] = (_Float16)v.x; h[1] = (_Float16)v.y;
    h[2] = (_Float16)v.z; h[3] = (_Float16)v.w;
  } else {
    h[0] = (_Float16)0.f; h[1] = (_Float16)0.f;
    h[2] = (_Float16)0.f; h[3] = (_Float16)0.f;
  }
  *(f16x4v*)(Bw + i) = h;
}

// ---------------------------------------------------------------------------
__device__ __forceinline__ void load_lds16(const void* g, void* l) {
  __builtin_amdgcn_global_load_lds((__attribute__((address_space(1))) unsigned int*)g,
                                   (__attribute__((address_space(3))) unsigned int*)l,
                                   16, 0, 0);
}

// C(2048x192) += A(2048x32768,f16) * Bw(192x32768,f16)^T, split-K partials.
__global__ __launch_bounds__(256, 2) void gemm_kernel(
    const _Float16* __restrict__ A, const _Float16* __restrict__ Bw,
    float* __restrict__ P, int kchunk) {
  __shared__ _Float16 As[128 * 64];  // 16 KB
  __shared__ _Float16 Bs[192 * 64];  // 24 KB
  const int tid = threadIdx.x;
  const int lane = tid & 63;
  const int wave = tid >> 6;
  const int m0 = blockIdx.x * 128;
  const int k0 = blockIdx.y * kchunk;
  const int nstages = kchunk >> 6;

  f32x4 acc[2][12];
#pragma unroll
  for (int mt = 0; mt < 2; ++mt)
#pragma unroll
    for (int nt = 0; nt < 12; ++nt) acc[mt][nt] = (f32x4){0.f, 0.f, 0.f, 0.f};

  for (int ks = 0; ks < nstages; ++ks) {
    const int kbase = k0 + (ks << 6);
    __syncthreads();
#pragma unroll
    for (int t = 0; t < 4; ++t) {
      int g = ((wave * 4 + t) << 6) + lane;
      int r = g >> 3, cs = g & 7;
      const _Float16* gp = A + (size_t)(m0 + r) * 32768 + kbase + ((cs ^ (r & 7)) << 3);
      load_lds16(gp, (char*)As + (size_t)((wave * 4 + t) << 10));
    }
#pragma unroll
    for (int t = 0; t < 6; ++t) {
      int g = ((wave * 6 + t) << 6) + lane;
      int r = g >> 3, cs = g & 7;
      const _Float16* gp = Bw + (size_t)r * 32768 + kbase + ((cs ^ (r & 7)) << 3);
      load_lds16(gp, (char*)Bs + (size_t)((wave * 6 + t) << 10));
    }
    __syncthreads();
#pragma unroll
    for (int kk = 0; kk < 2; ++kk) {
      const int chunk = kk * 4 + (lane >> 4);
      f16x8 af[2];
#pragma unroll
      for (int mt = 0; mt < 2; ++mt) {
        int r = wave * 32 + mt * 16 + (lane & 15);
        af[mt] = *(const f16x8*)(As + r * 64 + ((chunk ^ (r & 7)) << 3));
      }
#pragma unroll
      for (int nt = 0; nt < 12; ++nt) {
        int rb = nt * 16 + (lane & 15);
        f16x8 bf = *(const f16x8*)(Bs + rb * 64 + ((chunk ^ (rb & 7)) << 3));
        acc[0][nt] = __builtin_amdgcn_mfma_f32_16x16x32_f16(af[0], bf, acc[0][nt], 0, 0, 0);
        acc[1][nt] = __builtin_amdgcn_mfma_f32_16x16x32_f16(af[1], bf, acc[1][nt], 0, 0, 0);
      }
    }
  }
  float* Pp = P + ((size_t)blockIdx.y * 2048 + m0) * 192;
#pragma unroll
  for (int mt = 0; mt < 2; ++mt)
#pragma unroll
    for (int nt = 0; nt < 12; ++nt)
#pragma unroll
      for (int r4 = 0; r4 < 4; ++r4) {
        int rr = wave * 32 + mt * 16 + ((lane >> 4) << 2) + r4;
        int cc = nt * 16 + (lane & 15);
        Pp[(size_t)rr * 192 + cc] = acc[mt][nt][r4];
      }
}

// ---------------------------------------------------------------------------
__global__ __launch_bounds__(256) void mlp_kernel(
    const float* __restrict__ P, const float* __restrict__ b0,
    const float* __restrict__ W1, const float* __restrict__ b1,
    const float* __restrict__ W2, const float* __restrict__ b2,
    float* __restrict__ out, int nsplit) {
  __shared__ float h1[181];
  __shared__ float h2[13];
  const int row = blockIdx.x;
  const int t = threadIdx.x;
  if (t < 181) {
    float c = b0[t];
    for (int s = 0; s < nsplit; ++s)
      c += P[((size_t)s * 2048 + row) * 192 + t];
    h1[t] = fmaxf(c, 0.f);
  }
  __syncthreads();
  if (t < 13) {
    float c = b1[t];
    for (int n = 0; n < 181; ++n) c += h1[n] * W1[t * 181 + n];
    h2[t] = fmaxf(c, 0.f);
  }
  __syncthreads();
  if (t < 10) {
    float c = b2[t];
    for (int j = 0; j < 13; ++j) c += h2[j] * W2[t * 13 + j];
    out[(size_t)row * 10 + t] = c;
  }
}

// ---------------------------------------------------------------------------
extern "C" void kernel_launch(void* const* d_in, const int* in_sizes, int n_in,
                              void* d_out, int out_size, void* d_ws, size_t ws_size,
                              hipStream_t stream) {
  const float* x1 = (const float*)d_in[0];
  const float* W0 = (const float*)d_in[3];
  const float* b0 = (const float*)d_in[4];
  const float* W1 = (const float*)d_in[5];
  const float* b1 = (const float*)d_in[6];
  const float* W2 = (const float*)d_in[7];
  const float* b2 = (const float*)d_in[8];
  float* out = (float*)d_out;

  char* ws = (char*)d_ws;
  const size_t A_BYTES = (size_t)2048 * 32768 * 2;
  const size_t B_BYTES = (size_t)192 * 32768 * 2;
  _Float16* Afeat = (_Float16*)ws;
  _Float16* Bw = (_Float16*)(ws + A_BYTES);
  // D (2048*DROW*4 = 34 MB) aliases P (50 MB): D is dead before gemm writes P.
  float* Dq = (float*)(ws + A_BYTES + B_BYTES);
  float* P = (float*)(ws + A_BYTES + B_BYTES);

  int nsplit = 32;
  while (nsplit > 1 &&
         A_BYTES + B_BYTES + (size_t)nsplit * 2048 * 192 * 4 > ws_size)
    nsplit >>= 1;

  cvt_w0<<<6144, 256, 0, stream>>>(W0, Bw);
  wv_analysis<<<2048, WV_THREADS, 0, stream>>>(x1, Dq);
  dim3 sg(2048, 8);
  wv_synth<<<sg, WV_THREADS, 0, stream>>>(Dq, Afeat);
  dim3 gg(16, nsplit);
  gemm_kernel<<<gg, 256, 0, stream>>>(Afeat, Bw, P, 32768 / nsplit);
  mlp_kernel<<<2048, 256, 0, stream>>>(P, b0, W1, b1, W2, b2, out, nsplit);
}

// Round 4
// 228.219 us; speedup vs baseline: 1.7135x; 1.0641x over previous
//
#include <hip/hip_runtime.h>
#include <hip/hip_bf16.h>

// ---------------------------------------------------------------------------
// WaveletNauralNet: 9-level DWT -> 8 band reconstructions (h: 2048x32768,
// linear in x1) -> relu -> W0 (181x32768) -> relu -> W1 (13x181) -> relu ->
// W2 (10x13).
//   K1: fused [per-row analysis (d2..d9 via LDS, single d1 drain)] +
//       [W0 fp32->fp16 convert] in one heterogeneous grid
//   K2: per-(row,L) synthesis; small steps (dlen<=70) wave0-only, no barriers
//   K3: split-K MFMA fp16 GEMM (BM=128,BN=192,BK=64), fp32 partials
//   K4: reduce partials (4 wave-groups, coalesced) + MLP layers 1..2
// ---------------------------------------------------------------------------

typedef _Float16 f16x8 __attribute__((ext_vector_type(8)));
typedef _Float16 f16x4v __attribute__((ext_vector_type(4)));
typedef float f32x4 __attribute__((ext_vector_type(4)));

#define WV_THREADS 256
#define DROW 4144  // per-row float stride of packed d1..d9

// reconstruction filters
#define L0 0.23037781330885523f
#define L1 0.7148465705525415f
#define L2f 0.6308807679295904f
#define L3 -0.02798376941698385f
#define L4 -0.18703481171888114f
#define L5 0.030841381835986965f
#define L6 0.032883011666982945f
#define L7 -0.010597401784997278f

#define H0 -0.010597401784997278f
#define H1 -0.032883011666982945f
#define H2 0.030841381835986965f
#define H3 0.18703481171888114f
#define H4 -0.02798376941698385f
#define H5 -0.6308807679295904f
#define H6 0.7148465705525415f
#define H7 -0.23037781330885523f

__device__ __forceinline__ int ext_idx(int j, int n) {
  return (j < 6) ? (5 - j) : ((j < n + 6) ? (j - 6) : (2 * n + 5 - j));
}

// one DWT level, 2 outputs per thread, stride-1 lanes.
__device__ __forceinline__ void dwt2(const float* a, float* anext, float* d,
                                     int n, int m, bool store_a) {
  const int ng = (m + 1) >> 1;
  for (int g = threadIdx.x; g < ng; g += WV_THREADS) {
    float w[10];
    if (g >= 2 && 4 * g + 9 <= n + 5) {
      const float2* af = (const float2*)a + (2 * g - 3);
      float2 b0 = af[0], b1 = af[1], b2 = af[2], b3 = af[3], b4 = af[4];
      w[0] = b0.x; w[1] = b0.y; w[2] = b1.x; w[3] = b1.y; w[4] = b2.x;
      w[5] = b2.y; w[6] = b3.x; w[7] = b3.y; w[8] = b4.x; w[9] = b4.y;
    } else {
#pragma unroll
      for (int q = 0; q < 10; ++q) {
        int j = 4 * g + q;
        int jm = n + 12;
        if (j > jm) j = jm;
        w[q] = a[ext_idx(j, n)];
      }
    }
    float sl0 = w[0]*L0 + w[1]*L1 + w[2]*L2f + w[3]*L3 + w[4]*L4 + w[5]*L5 + w[6]*L6 + w[7]*L7;
    float sh0 = w[0]*H0 + w[1]*H1 + w[2]*H2  + w[3]*H3 + w[4]*H4 + w[5]*H5 + w[6]*H6 + w[7]*H7;
    float sl1 = w[2]*L0 + w[3]*L1 + w[4]*L2f + w[5]*L3 + w[6]*L4 + w[7]*L5 + w[8]*L6 + w[9]*L7;
    float sh1 = w[2]*H0 + w[3]*H1 + w[4]*H2  + w[5]*H3 + w[6]*H4 + w[7]*H5 + w[8]*H6 + w[9]*H7;
    if (2 * g + 1 < m) {
      if (store_a) *(float2*)(anext + 2 * g) = make_float2(sl0, sl1);
      *(float2*)(d + 2 * g) = make_float2(sh0, sh1);
    } else {
      if (store_a) anext[2 * g] = sl0;
      d[2 * g] = sh0;
    }
  }
}

// one IDWT step, 2 pairs per thread. npair = dlen-3, olen = 2*dlen-6.
template <bool HAS_CA, bool HAS_CD, bool FINAL>
__device__ __forceinline__ void idwt2(const float* ca, const float* cd,
                                      float* outl, _Float16* outg, int dlen) {
  const int npair = dlen - 3;
  const int ng = (npair + 1) >> 1;
  for (int g = threadIdx.x; g < ng; g += WV_THREADS) {
    float e0 = 0.f, o0 = 0.f, e1 = 0.f, o1 = 0.f;
    if (HAS_CA) {
      const float2* f = (const float2*)ca + g;
      float2 a0 = f[0], a1 = f[1], a2 = f[2];
      e0 = a1.y*L0 + a1.x*L2f + a0.y*L4 + a0.x*L6;
      o0 = a1.y*L1 + a1.x*L3  + a0.y*L5 + a0.x*L7;
      e1 = a2.x*L0 + a1.y*L2f + a1.x*L4 + a0.y*L6;
      o1 = a2.x*L1 + a1.y*L3  + a1.x*L5 + a0.y*L7;
    }
    if (HAS_CD) {
      const float2* f = (const float2*)cd + g;
      float2 d0 = f[0], d1 = f[1], d2 = f[2];
      e0 += d1.y*H0 + d1.x*H2 + d0.y*H4 + d0.x*H6;
      o0 += d1.y*H1 + d1.x*H3 + d0.y*H5 + d0.x*H7;
      e1 += d2.x*H0 + d1.y*H2 + d1.x*H4 + d0.y*H6;
      o1 += d2.x*H1 + d1.y*H3 + d1.x*H5 + d0.y*H7;
    }
    bool full = (2 * g + 1 < npair);
    if (FINAL) {
      if (full) {
        f16x4v h;
        h[0] = (_Float16)fmaxf(e0, 0.f); h[1] = (_Float16)fmaxf(o0, 0.f);
        h[2] = (_Float16)fmaxf(e1, 0.f); h[3] = (_Float16)fmaxf(o1, 0.f);
        *(f16x4v*)(outg + 4 * g) = h;
      } else {
        outg[4 * g]     = (_Float16)fmaxf(e0, 0.f);
        outg[4 * g + 1] = (_Float16)fmaxf(o0, 0.f);
      }
    } else {
      if (full) *(float4*)(outl + 4 * g) = make_float4(e0, o0, e1, o1);
      else      *(float2*)(outl + 4 * g) = make_float2(e0, o0);
    }
  }
}

// ---------------------------------------------------------------------------
// Fused: blocks [0,2048) = analysis rows; blocks [2048, 2048+6144) = W0 cvt.
// Analysis LDS liveness layout (r1[4104], r2[2056] = 24.6 KB -> 6 blk/CU):
//   r1: a-even @0 (a0 4096, a2 1029, a4 262, a6 70, a8 22)
//       d2@1036(1029) d4@2068(262) d6@2332(70) d8@2404(22)  [a0 dead from lev2]
//   r2: a-odd @0 (a1 2051, a3 518, a5 134, a7 38)
//       d3@520(518) d5@1040(134) d7@1176(38) d9@1216(14)    [a1 dead from lev3]
//   d1 -> global direct (only vmcnt drain in the chain).
__global__ __launch_bounds__(WV_THREADS) void wv_analysis_cvt(
    const float* __restrict__ x, float* __restrict__ dG,
    const float* __restrict__ W0, _Float16* __restrict__ Bw) {
  __shared__ float r1[4104];
  __shared__ float r2[2056];
  const int tid = threadIdx.x;

  if (blockIdx.x >= 2048) {  // ---- cvt path ----
    size_t i = ((size_t)(blockIdx.x - 2048) * 256 + tid) * 4;
    int rowc = (int)(i >> 15);
    f16x4v h;
    if (rowc < 181) {
      const float4 v = *(const float4*)(W0 + i);
      h[0] = (_Float16)v.x; h[1] = (_Float16)v.y;
      h[2] = (_Float16)v.z; h[3] = (_Float16)v.w;
    } else {
      h[0] = (_Float16)0.f; h[1] = (_Float16)0.f;
      h[2] = (_Float16)0.f; h[3] = (_Float16)0.f;
    }
    *(f16x4v*)(Bw + i) = h;
    return;
  }

  const int NLa[10]  = {4096, 2051, 1029, 518, 262, 134, 70, 38, 22, 14};
  const int DOFF[10] = {0, 0, 2052, 3082, 3600, 3862, 3996, 4066, 4104, 4126};
  // LDS offsets for d2..d9 (index by level), buffer = (lev even ? r1 : r2)
  const int LOFF[10] = {0, 0, 1036, 520, 2068, 1040, 2332, 1176, 2404, 1216};
  const int row = blockIdx.x;

  const float4* xr = (const float4*)(x + (size_t)row * 4096);
  for (int i = tid; i < 1024; i += WV_THREADS) ((float4*)r1)[i] = xr[i];
  __syncthreads();

  float* dr = dG + (size_t)row * DROW;
  // lev1: a0(r1) -> a1(r2), d1 -> global
  dwt2(r1, r2, dr + DOFF[1], NLa[0], NLa[1], true);
  __syncthreads();
  // lev2..9: d -> LDS tails
  const float* ap = r2;
  float* an = r1;
  for (int lev = 2; lev <= 9; ++lev) {
    float* dbuf = ((lev & 1) ? r2 : r1) + LOFF[lev];
    dwt2(ap, an, dbuf, NLa[lev - 1], NLa[lev], lev < 9);
    __syncthreads();
    const float* t = ap; ap = an; an = (float*)t;
  }
  // copy-out d2..d9 (coalesced)
  for (int lev = 2; lev <= 9; ++lev) {
    const float* src = ((lev & 1) ? r2 : r1) + LOFF[lev];
    float* dst = dr + DOFF[lev];
    for (int i = tid; i < NLa[lev]; i += WV_THREADS) dst[i] = src[i];
  }
}

// ---------------------------------------------------------------------------
// Synthesis: one block per (row, L=2+blockIdx.y). Steps with dlen<=70 run in
// wave 0 only (intra-wave lgkmcnt ordering; dlen grows monotonically so a
// single __syncthreads publishes the prefix).
__global__ __launch_bounds__(WV_THREADS, 6) void wv_synth(
    const float* __restrict__ dG, _Float16* __restrict__ A) {
  __shared__ float s1[2052];
  __shared__ float s2[2052];
  const int NLa[10]  = {4096, 2051, 1029, 518, 262, 134, 70, 38, 22, 14};
  const int DOFF[10] = {0, 0, 2052, 3082, 3600, 3862, 3996, 4066, 4104, 4126};
  const int row = blockIdx.x;
  const int L = 2 + blockIdx.y;
  const int tid = threadIdx.x;
  const float* dr = dG + (size_t)row * DROW;

  float* cur = s1;
  float* nxt = s2;
  int startj = L - 2;
  if (L >= 6) {
    if (tid < 64) {
      idwt2<false, true, false>(nullptr, dr + DOFF[L], cur, nullptr, NLa[L]);
      asm volatile("s_waitcnt lgkmcnt(0)" ::: "memory");
      for (int j = L - 2; j >= 5; --j) {
        if (j == L - 2)
          idwt2<true, true, false>(cur, dr + DOFF[j + 1], nxt, nullptr, NLa[j + 1]);
        else
          idwt2<true, false, false>(cur, nullptr, nxt, nullptr, NLa[j + 1]);
        asm volatile("s_waitcnt lgkmcnt(0)" ::: "memory");
        float* t = cur; cur = nxt; nxt = t;
      }
    } else {
      for (int j = L - 2; j >= 5; --j) { float* t = cur; cur = nxt; nxt = t; }
    }
    __syncthreads();
    startj = 4;
  } else {
    idwt2<false, true, false>(nullptr, dr + DOFF[L], cur, nullptr, NLa[L]);
    __syncthreads();
  }
  for (int j = startj; j >= 1; --j) {
    if (j == L - 2)
      idwt2<true, true, false>(cur, dr + DOFF[j + 1], nxt, nullptr, NLa[j + 1]);
    else
      idwt2<true, false, false>(cur, nullptr, nxt, nullptr, NLa[j + 1]);
    __syncthreads();
    float* t = cur; cur = nxt; nxt = t;
  }
  _Float16* og = A + (size_t)row * 32768 + (size_t)(L - 2) * 4096;
  if (L == 2)
    idwt2<true, true, true>(cur, dr + DOFF[1], nullptr, og, 2051);
  else
    idwt2<true, false, true>(cur, nullptr, nullptr, og, 2051);
}

// ---------------------------------------------------------------------------
__device__ __forceinline__ void load_lds16(const void* g, void* l) {
  __builtin_amdgcn_global_load_lds((__attribute__((address_space(1))) unsigned int*)g,
                                   (__attribute__((address_space(3))) unsigned int*)l,
                                   16, 0, 0);
}

// C(2048x192) += A(2048x32768,f16) * Bw(192x32768,f16)^T, split-K partials.
__global__ __launch_bounds__(256, 2) void gemm_kernel(
    const _Float16* __restrict__ A, const _Float16* __restrict__ Bw,
    float* __restrict__ P, int kchunk) {
  __shared__ _Float16 As[128 * 64];  // 16 KB
  __shared__ _Float16 Bs[192 * 64];  // 24 KB
  const int tid = threadIdx.x;
  const int lane = tid & 63;
  const int wave = tid >> 6;
  const int m0 = blockIdx.x * 128;
  const int k0 = blockIdx.y * kchunk;
  const int nstages = kchunk >> 6;

  f32x4 acc[2][12];
#pragma unroll
  for (int mt = 0; mt < 2; ++mt)
#pragma unroll
    for (int nt = 0; nt < 12; ++nt) acc[mt][nt] = (f32x4){0.f, 0.f, 0.f, 0.f};

  for (int ks = 0; ks < nstages; ++ks) {
    const int kbase = k0 + (ks << 6);
    __syncthreads();
#pragma unroll
    for (int t = 0; t < 4; ++t) {
      int g = ((wave * 4 + t) << 6) + lane;
      int r = g >> 3, cs = g & 7;
      const _Float16* gp = A + (size_t)(m0 + r) * 32768 + kbase + ((cs ^ (r & 7)) << 3);
      load_lds16(gp, (char*)As + (size_t)((wave * 4 + t) << 10));
    }
#pragma unroll
    for (int t = 0; t < 6; ++t) {
      int g = ((wave * 6 + t) << 6) + lane;
      int r = g >> 3, cs = g & 7;
      const _Float16* gp = Bw + (size_t)r * 32768 + kbase + ((cs ^ (r & 7)) << 3);
      load_lds16(gp, (char*)Bs + (size_t)((wave * 6 + t) << 10));
    }
    __syncthreads();
#pragma unroll
    for (int kk = 0; kk < 2; ++kk) {
      const int chunk = kk * 4 + (lane >> 4);
      f16x8 af[2];
#pragma unroll
      for (int mt = 0; mt < 2; ++mt) {
        int r = wave * 32 + mt * 16 + (lane & 15);
        af[mt] = *(const f16x8*)(As + r * 64 + ((chunk ^ (r & 7)) << 3));
      }
#pragma unroll
      for (int nt = 0; nt < 12; ++nt) {
        int rb = nt * 16 + (lane & 15);
        f16x8 bf = *(const f16x8*)(Bs + rb * 64 + ((chunk ^ (rb & 7)) << 3));
        acc[0][nt] = __builtin_amdgcn_mfma_f32_16x16x32_f16(af[0], bf, acc[0][nt], 0, 0, 0);
        acc[1][nt] = __builtin_amdgcn_mfma_f32_16x16x32_f16(af[1], bf, acc[1][nt], 0, 0, 0);
      }
    }
  }
  float* Pp = P + ((size_t)blockIdx.y * 2048 + m0) * 192;
#pragma unroll
  for (int mt = 0; mt < 2; ++mt)
#pragma unroll
    for (int nt = 0; nt < 12; ++nt)
#pragma unroll
      for (int r4 = 0; r4 < 4; ++r4) {
        int rr = wave * 32 + mt * 16 + ((lane >> 4) << 2) + r4;
        int cc = nt * 16 + (lane & 15);
        Pp[(size_t)rr * 192 + cc] = acc[mt][nt][r4];
      }
}

// ---------------------------------------------------------------------------
// P reduce: 4 wave-groups x 8 splits, coalesced 64-lane loads; then layer1
// bias+relu, layer2 via wave-shuffle dots, layer3 scalar.
__global__ __launch_bounds__(256) void mlp_kernel(
    const float* __restrict__ P, const float* __restrict__ b0,
    const float* __restrict__ W1, const float* __restrict__ b1,
    const float* __restrict__ W2, const float* __restrict__ b2,
    float* __restrict__ out, int nsplit) {
  __shared__ float part[4][193];
  __shared__ float h1[192];
  __shared__ float h2[13];
  const int row = blockIdx.x;
  const int t = threadIdx.x;
  const int g = t >> 6;
  const int l = t & 63;

  float a0 = 0.f, a1 = 0.f, a2 = 0.f;
  const int per = nsplit >> 2;  // splits per group
  for (int si = 0; si < per; ++si) {
    int s = g + (si << 2);
    const float* Pr = P + ((size_t)s * 2048 + row) * 192;
    a0 += Pr[l]; a1 += Pr[64 + l]; a2 += Pr[128 + l];
  }
  part[g][l] = a0; part[g][64 + l] = a1; part[g][128 + l] = a2;
  __syncthreads();

  if (t < 192) {
    float v = part[0][t] + part[1][t] + part[2][t] + part[3][t];
    h1[t] = (t < 181) ? fmaxf(v + b0[t], 0.f) : 0.f;
  }
  __syncthreads();

  // layer 2: 13 outputs; wave g handles j = g, g+4, g+8, g+12 (<13)
#pragma unroll
  for (int r = 0; r < 4; ++r) {
    int j = g + (r << 2);
    if (j < 13) {
      float v = 0.f;
#pragma unroll
      for (int q = 0; q < 3; ++q) {
        int n = l + (q << 6);
        if (n < 181) v += h1[n] * W1[j * 181 + n];
      }
      for (int off = 32; off >= 1; off >>= 1) v += __shfl_down(v, off);
      if (l == 0) h2[j] = fmaxf(v + b1[j], 0.f);
    }
  }
  __syncthreads();

  if (t < 10) {
    float c = b2[t];
#pragma unroll
    for (int j = 0; j < 13; ++j) c += h2[j] * W2[t * 13 + j];
    out[(size_t)row * 10 + t] = c;
  }
}

// ---------------------------------------------------------------------------
extern "C" void kernel_launch(void* const* d_in, const int* in_sizes, int n_in,
                              void* d_out, int out_size, void* d_ws, size_t ws_size,
                              hipStream_t stream) {
  const float* x1 = (const float*)d_in[0];
  const float* W0 = (const float*)d_in[3];
  const float* b0 = (const float*)d_in[4];
  const float* W1 = (const float*)d_in[5];
  const float* b1 = (const float*)d_in[6];
  const float* W2 = (const float*)d_in[7];
  const float* b2 = (const float*)d_in[8];
  float* out = (float*)d_out;

  char* ws = (char*)d_ws;
  const size_t A_BYTES = (size_t)2048 * 32768 * 2;
  const size_t B_BYTES = (size_t)192 * 32768 * 2;
  _Float16* Afeat = (_Float16*)ws;
  _Float16* Bw = (_Float16*)(ws + A_BYTES);
  // D (2048*DROW*4 = 34 MB) aliases P (50 MB): D dead before gemm writes P.
  float* Dq = (float*)(ws + A_BYTES + B_BYTES);
  float* P = (float*)(ws + A_BYTES + B_BYTES);

  int nsplit = 32;
  while (nsplit > 1 &&
         A_BYTES + B_BYTES + (size_t)nsplit * 2048 * 192 * 4 > ws_size)
    nsplit >>= 1;

  wv_analysis_cvt<<<2048 + 6144, WV_THREADS, 0, stream>>>(x1, Dq, W0, Bw);
  dim3 sg(2048, 8);
  wv_synth<<<sg, WV_THREADS, 0, stream>>>(Dq, Afeat);
  dim3 gg(16, nsplit);
  gemm_kernel<<<gg, 256, 0, stream>>>(Afeat, Bw, P, 32768 / nsplit);
  mlp_kernel<<<2048, 256, 0, stream>>>(P, b0, W1, b1, W2, b2, out, nsplit);
}